// Round 8
// baseline (487.551 us; speedup 1.0000x reference)
//
#include <hip/hip_runtime.h>
#include <hip/hip_bf16.h>

using bf16 = __hip_bfloat16;
typedef short  short8  __attribute__((ext_vector_type(8)));
typedef float  float4_ __attribute__((ext_vector_type(4)));
typedef int    int4_   __attribute__((ext_vector_type(4)));

typedef __attribute__((address_space(1))) const void* gas_ptr;
typedef __attribute__((address_space(3))) void*       las_ptr;

#define MFMA_BF16(a, b, c) __builtin_amdgcn_mfma_f32_16x16x32_bf16((a), (b), (c), 0, 0, 0)

__device__ __forceinline__ float bf2f(bf16 v) { return __bfloat162float(v); }
__device__ __forceinline__ bf16  f2bf(float v) { return __float2bfloat16(v); }

#define BAR() do { asm volatile("" ::: "memory"); __builtin_amdgcn_s_barrier(); asm volatile("" ::: "memory"); } while (0)
#define WAITLGKM0() asm volatile("s_waitcnt lgkmcnt(0)" ::: "memory")

// ---------------------------------------------------------------------------
// DPP 16-lane reductions (verified r7): groups = lanes [quad*16..quad*16+15].
// ---------------------------------------------------------------------------
template<int CTRL>
__device__ __forceinline__ float dppmv(float x) {
    return __int_as_float(__builtin_amdgcn_update_dpp(
        0, __float_as_int(x), CTRL, 0xF, 0xF, true));
}
__device__ __forceinline__ float row16_max(float x) {
    x = fmaxf(x, dppmv<0xB1>(x));
    x = fmaxf(x, dppmv<0x4E>(x));
    x = fmaxf(x, dppmv<0x124>(x));
    x = fmaxf(x, dppmv<0x128>(x));
    return x;
}
__device__ __forceinline__ float row16_sum(float x) {
    x += dppmv<0xB1>(x);
    x += dppmv<0x4E>(x);
    x += dppmv<0x124>(x);
    x += dppmv<0x128>(x);
    return x;
}

// ---------------------------------------------------------------------------
// fp32 -> bf16 conversion of X + 4 weights into workspace (verified r2 form).
// ---------------------------------------------------------------------------
__global__ __launch_bounds__(256)
void cvt_all(const float* __restrict__ X,  const float* __restrict__ Wq,
             const float* __restrict__ Wk, const float* __restrict__ Wv,
             const float* __restrict__ Wo,
             bf16* __restrict__ Xb,  bf16* __restrict__ Wqb,
             bf16* __restrict__ Wkb, bf16* __restrict__ Wvb,
             bf16* __restrict__ Wob)
{
    const size_t i = ((size_t)blockIdx.x * 256 + threadIdx.x) * 8;
    const float* src; bf16* dst; size_t off;
    if (i < 8388608)       { src = X;  dst = Xb;  off = i; }
    else if (i < 12582912) { src = Wq; dst = Wqb; off = i - 8388608; }
    else if (i < 16777216) { src = Wk; dst = Wkb; off = i - 12582912; }
    else if (i < 20971520) { src = Wv; dst = Wvb; off = i - 16777216; }
    else                   { src = Wo; dst = Wob; off = i - 20971520; }
    const float4_ a = *(const float4_*)(src + off);
    const float4_ b = *(const float4_*)(src + off + 4);
    union { short8 s; bf16 h[8]; } u;
#pragma unroll
    for (int j = 0; j < 4; ++j) { u.h[j] = f2bf(a[j]); u.h[j + 4] = f2bf(b[j]); }
    *(short8*)(dst + off) = u.s;
}

// ---------------------------------------------------------------------------
// 256x128 2-phase-per-tile MFMA GEMM (verified r4-r7). FROZEN.
// mode 0: scatter bf16 to Oq = q/k/v [3][B][NH][S][HD], N=6144 merged QKV.
// mode 1: row-major fp32 OF, N=2048.
// ---------------------------------------------------------------------------
__global__ __launch_bounds__(512, 2)
void gemm_bn128(const bf16* __restrict__ Ap, const bf16* __restrict__ Wp,
                bf16* __restrict__ Oq, float* __restrict__ OF, int mode)
{
    constexpr int NT = 32;                       // K=2048 / BK=64
    __shared__ bf16 As0[2 * 256 * 64];           // 64 KiB [buf][row][64]
    __shared__ bf16 Bs0[2 * 128 * 64];           // 32 KiB

    const int nwg  = gridDim.x * gridDim.y;
    const int bid0 = blockIdx.y * gridDim.x + blockIdx.x;
    const int cpx  = nwg >> 3;
    const int swzb = (bid0 & 7) * cpx + (bid0 >> 3);
    const int bn = (swzb % gridDim.x) * 128;
    const int bm = (swzb / gridDim.x) * 256;

    const int tid  = threadIdx.x;
    const int w    = tid >> 6;                   // 0..7
    const int ln   = tid & 63;
    const int r15  = ln & 15;
    const int quad = ln >> 4;
    const int wr   = w >> 1;                     // 0..3 (M)
    const int wc   = w & 1;                      // 0..1 (N)

    const int srow = ln >> 3;                                // 0..7
    const int scol = ((ln & 7) ^ srow) * 8;                  // elements
    const int w8   = w * 8;
    const int cx   = (r15 & 7) * 8;                          // read-side XOR

#define STAGE_A(pb, ts) do {                                                \
    _Pragma("unroll")                                                       \
    for (int c = 0; c < 4; ++c) {                                           \
        const int rl = c * 64 + w8;                                         \
        __builtin_amdgcn_global_load_lds(                                   \
            (gas_ptr)(Ap + (size_t)(bm + rl + srow) * 2048 + (ts) * 64 + scol), \
            (las_ptr)(As0 + (pb) * 16384 + rl * 64), 16, 0, 0);             \
    } } while (0)

#define STAGE_B0(pb, ts) do {                                               \
    const int rl = w8;                                                      \
    __builtin_amdgcn_global_load_lds(                                       \
        (gas_ptr)(Wp + (size_t)(bn + rl + srow) * 2048 + (ts) * 64 + scol), \
        (las_ptr)(Bs0 + (pb) * 8192 + rl * 64), 16, 0, 0);                  \
    } while (0)

#define STAGE_B1(pb, ts) do {                                               \
    const int rl = 64 + w8;                                                 \
    __builtin_amdgcn_global_load_lds(                                       \
        (gas_ptr)(Wp + (size_t)(bn + rl + srow) * 2048 + (ts) * 64 + scol), \
        (las_ptr)(Bs0 + (pb) * 8192 + rl * 64), 16, 0, 0);                  \
    } while (0)

#define LDA() do {                                                          \
    _Pragma("unroll")                                                       \
    for (int mi = 0; mi < 4; ++mi) {                                        \
        const int row = wr * 64 + mi * 16 + r15;                            \
        a[mi][0] = *(const short8*)(As0 + p * 16384 + row * 64 + ((quad * 8) ^ cx));      \
        a[mi][1] = *(const short8*)(As0 + p * 16384 + row * 64 + ((32 + quad * 8) ^ cx)); \
    } } while (0)

#define LDB(qn) do {                                                        \
    _Pragma("unroll")                                                       \
    for (int j = 0; j < 2; ++j) {                                           \
        const int row = wc * 64 + ((qn) * 2 + j) * 16 + r15;                \
        b[j][0] = *(const short8*)(Bs0 + p * 8192 + row * 64 + ((quad * 8) ^ cx));      \
        b[j][1] = *(const short8*)(Bs0 + p * 8192 + row * 64 + ((32 + quad * 8) ^ cx)); \
    } } while (0)

#define MM(qn) do {                                                         \
    __builtin_amdgcn_s_setprio(1);                                          \
    _Pragma("unroll")                                                       \
    for (int mi = 0; mi < 4; ++mi)                                          \
        _Pragma("unroll")                                                   \
        for (int j = 0; j < 2; ++j)                                         \
            _Pragma("unroll")                                               \
            for (int kk = 0; kk < 2; ++kk)                                  \
                acc[mi][(qn) * 2 + j] =                                     \
                    MFMA_BF16(a[mi][kk], b[j][kk], acc[mi][(qn) * 2 + j]);  \
    __builtin_amdgcn_s_setprio(0); } while (0)

    float4_ acc[4][4];
    const float4_ fzero = {0.f, 0.f, 0.f, 0.f};
#pragma unroll
    for (int i = 0; i < 4; ++i)
#pragma unroll
        for (int j = 0; j < 4; ++j) acc[i][j] = fzero;

    short8 a[4][2], b[2][2];

    STAGE_A(0, 0); STAGE_B0(0, 0); STAGE_B1(0, 0);
    STAGE_A(1, 1); STAGE_B0(1, 1);
    asm volatile("s_waitcnt vmcnt(5)" ::: "memory");
    BAR();

    for (int t = 0; t < NT; ++t) {
        const int p = t & 1, pq = p ^ 1;
        LDA(); LDB(0);
        if (t + 1 < NT) STAGE_B1(pq, t + 1);
        asm volatile("s_waitcnt lgkmcnt(8)" ::: "memory");
        BAR(); WAITLGKM0();
        MM(0);
        BAR();
        LDB(1);
        if (t + 2 < NT) { STAGE_A(p, t + 2); STAGE_B0(p, t + 2); }
        BAR(); WAITLGKM0();
        MM(1);
        if (t >= NT - 2) { asm volatile("s_waitcnt vmcnt(0)" ::: "memory"); }
        else             { asm volatile("s_waitcnt vmcnt(5)" ::: "memory"); }
        BAR();
    }

#pragma unroll
    for (int mi = 0; mi < 4; ++mi) {
#pragma unroll
        for (int ni = 0; ni < 4; ++ni) {
#pragma unroll
            for (int r = 0; r < 4; ++r) {
                const int row = bm + wr * 64 + mi * 16 + quad * 4 + r;
                const int col = bn + wc * 64 + ni * 16 + r15;
                const float v = acc[mi][ni][r];
                if (mode == 0) {
                    const int z = col >> 11, c2 = col & 2047;
                    const int h = c2 >> 7, d = c2 & 127;
                    const int bb = row >> 11, s = row & 2047;
                    Oq[(size_t)z * 8388608 + (((size_t)bb * 16 + h) * 2048 + s) * 128 + d] = f2bf(v);
                } else {
                    OF[(size_t)row * 2048 + col] = v;
                }
            }
        }
    }
#undef STAGE_A
#undef STAGE_B0
#undef STAGE_B1
#undef LDA
#undef LDB
#undef MM
}

// ---------------------------------------------------------------------------
// RoPE cos/sin table: tab[s][d] = (cos, sin) of s * theta^(-d/64), d<64.
// 131072 entries (1 MB) computed once instead of 32x per (s,d) in rope_scale.
// ---------------------------------------------------------------------------
__global__ __launch_bounds__(256)
void rope_tab(float2* __restrict__ tab)
{
    const int i = blockIdx.x * 256 + threadIdx.x;   // 0..131071
    const int d = i & 63;
    const int s = i >> 6;
    const float inv_freq = expf(-(float)d * (9.210340371976184f / 64.f));
    const float ang = (float)s * inv_freq;
    tab[i] = make_float2(cosf(ang), sinf(ang));
}

// ---------------------------------------------------------------------------
// RoPE on Q and K ([B][NH][S][HD] bf16) from table; folds 1/sqrt(128) into Q.
// ---------------------------------------------------------------------------
__global__ __launch_bounds__(256)
void rope_scale(bf16* __restrict__ Q, bf16* __restrict__ Kb,
                const float2* __restrict__ tab)
{
    const int idx = blockIdx.x * 256 + threadIdx.x;
    const int d  = idx & 63;
    const int s  = (idx >> 6) & 2047;
    const int bh = idx >> 17;
    const size_t base = ((size_t)bh * 2048 + s) * 128;

    const float2 cs = tab[s * 64 + d];
    const float c = cs.x, sn = cs.y;
    const float sc = 0.08838834764831845f;

    const float q1 = bf2f(Q[base + d]), q2 = bf2f(Q[base + d + 64]);
    Q[base + d]      = f2bf((q1 * c - q2 * sn) * sc);
    Q[base + d + 64] = f2bf((q2 * c + q1 * sn) * sc);

    const float k1 = bf2f(Kb[base + d]), k2 = bf2f(Kb[base + d + 64]);
    Kb[base + d]      = f2bf(k1 * c - k2 * sn);
    Kb[base + d + 64] = f2bf(k2 * c + k1 * sn);
}

// ---------------------------------------------------------------------------
// Causal MFMA flash attention, v6 (64-row strip pairs, 2 blocks/CU):
//  - block (p,bh), p=0..15, owns strips p and 31-p (64 rows each): work =
//    (p+1)+(32-p) = 33 tiles, uniform. Grid 512 blocks; LDS 54.2 KB ->
//    2 blocks/CU, so one block's lo-idle tail is filled by the co-resident
//    block (fixes r5-r7's 1.4/2-waves-busy hole: pair-balance equalized
//    block runtimes, not wave timelines).
//  - 4 waves / 256 threads; each wave: 16 rows of strip-lo (rf0) + 16 rows
//    of strip-hi (rf1), sharing every kf/vf LDS read across frags.
//  - lo-frag gated by ONE block-uniform branch (both-frags path / hi-only
//    path); diagonal mask ro = wave*16+quad*4 identical for both frags.
//  - inner math verbatim from r7 (DPP softmax, T13 defer-max, T14 split).
// Q,K,V: [B][NH][S][HD] bf16 (Q pre-scaled); O: [B][S][NH][HD] bf16.
// ---------------------------------------------------------------------------
__global__ __launch_bounds__(256)
void flash_attn(const bf16* __restrict__ Qg, const bf16* __restrict__ Kg,
                const bf16* __restrict__ Vg, bf16* __restrict__ Og)
{
    constexpr int S = 2048;
    const int p  = blockIdx.x;            // 0..15: strip pair (p, 31-p)
    const int bh = blockIdx.y;
    const int b = bh >> 4, h = bh & 15;
    const size_t base = (size_t)bh * S * 128;
    const bf16* Qp = Qg + base;
    const bf16* Kp = Kg + base;
    const bf16* Vp = Vg + base;

    const int tid  = threadIdx.x;
    const int wave = tid >> 6;            // 0..3
    const int ln   = tid & 63;
    const int r15  = ln & 15;
    const int quad = ln >> 4;

    __shared__ bf16 Ks[64][136];          // K tile, 17.0 KB
    __shared__ bf16 Vt[128][72];          // V tile transposed, 18.0 KB
    __shared__ bf16 Ps[4][32][72];        // per-wave P (2 frags), 18.4 KB

    const int qlo   = p * 64 + wave * 16;         // rf0 rows
    const int qhi   = (31 - p) * 64 + wave * 16;  // rf1 rows
    const int dtlo  = p;                          // rf0 diagonal tile
    const int ktmax = 31 - p;                     // rf1 diagonal = last tile
    const int ro    = wave * 16 + quad * 4;       // row-in-tile (both frags)

    short8 qf[2][4];
#pragma unroll
    for (int ks = 0; ks < 4; ++ks) {
        qf[0][ks] = *(const short8*)&Qp[(size_t)(qlo + r15) * 128 + ks * 32 + quad * 8];
        qf[1][ks] = *(const short8*)&Qp[(size_t)(qhi + r15) * 128 + ks * 32 + quad * 8];
    }

    float4_ acc_o[2][8];
    const float4_ fzero = {0.f, 0.f, 0.f, 0.f};
#pragma unroll
    for (int rf = 0; rf < 2; ++rf)
#pragma unroll
        for (int of = 0; of < 8; ++of) acc_o[rf][of] = fzero;
    float m_run[2][4], l_run[2][4];
#pragma unroll
    for (int rf = 0; rf < 2; ++rf)
#pragma unroll
        for (int r = 0; r < 4; ++r) { m_run[rf][r] = -__builtin_inff(); l_run[rf][r] = 0.f; }

    // staging coords (256 threads)
    const int kr = tid >> 4;              // 0..15 (K row base, 4 passes)
    const int kc = (tid & 15) * 8;        // 0..120
    const int vd = wave * 32;             // V d-col base (32 cols/wave)

    {   // stage tile 0 synchronously
#pragma unroll
        for (int pp = 0; pp < 4; ++pp)
            *(int4_*)&Ks[kr + pp * 16][kc] =
                *(const int4_*)&Kp[(size_t)(kr + pp * 16) * 128 + kc];
        union { int4_ v; bf16 h[8]; } u;
#pragma unroll
        for (int pp = 0; pp < 4; ++pp) {
            u.v = *(const int4_*)&Vp[(size_t)ln * 128 + vd + pp * 8];
#pragma unroll
            for (int j = 0; j < 8; ++j)
                Vt[vd + pp * 8 + j][ln] = u.h[j];
        }
    }
    __syncthreads();

    // per-frag softmax (DPP reduce + T13 defer-max), writes Ps row block rf*16
#define SOFTMAX(rfi) do {                                                   \
        float rm4[4]; float g = 0.f;                                        \
        _Pragma("unroll")                                                   \
        for (int r = 0; r < 4; ++r) {                                       \
            float rm = fmaxf(fmaxf(sacc[rfi][0][r], sacc[rfi][1][r]),       \
                             fmaxf(sacc[rfi][2][r], sacc[rfi][3][r]));      \
            rm4[r] = row16_max(rm);                                         \
            g = fmaxf(g, rm4[r] - m_run[rfi][r]);                           \
        }                                                                   \
        const bool resc = !__all(g <= 8.f);                                 \
        float mnew[4];                                                      \
        if (resc) {                                                         \
            float alpha[4];                                                 \
            _Pragma("unroll")                                               \
            for (int r = 0; r < 4; ++r) {                                   \
                mnew[r]  = fmaxf(m_run[rfi][r], rm4[r]);                    \
                alpha[r] = __expf(m_run[rfi][r] - mnew[r]);                 \
                m_run[rfi][r] = mnew[r];                                    \
            }                                                               \
            _Pragma("unroll")                                               \
            for (int r = 0; r < 4; ++r) l_run[rfi][r] *= alpha[r];          \
            _Pragma("unroll")                                               \
            for (int of = 0; of < 8; ++of)                                  \
                _Pragma("unroll")                                           \
                for (int r = 0; r < 4; ++r)                                 \
                    acc_o[rfi][of][r] *= alpha[r];                          \
        } else {                                                            \
            _Pragma("unroll")                                               \
            for (int r = 0; r < 4; ++r) mnew[r] = m_run[rfi][r];            \
        }                                                                   \
        float rs[4] = {0.f, 0.f, 0.f, 0.f};                                 \
        _Pragma("unroll")                                                   \
        for (int nf = 0; nf < 4; ++nf)                                      \
            _Pragma("unroll")                                               \
            for (int r = 0; r < 4; ++r) {                                   \
                const float pp2 = __expf(sacc[rfi][nf][r] - mnew[r]);       \
                rs[r] += pp2;                                               \
                Ps[wave][(rfi) * 16 + quad * 4 + r][nf * 16 + r15] = f2bf(pp2); \
            }                                                               \
        _Pragma("unroll")                                                   \
        for (int r = 0; r < 4; ++r) l_run[rfi][r] += row16_sum(rs[r]);      \
    } while (0)

#define DIAGMASK(rfi) do {                                                  \
        _Pragma("unroll")                                                   \
        for (int nf = 0; nf < 4; ++nf) {                                    \
            const int col = nf * 16 + r15;                                  \
            _Pragma("unroll")                                               \
            for (int r = 0; r < 4; ++r)                                     \
                if (col > ro + r) sacc[rfi][nf][r] = -__builtin_inff();     \
        }                                                                   \
    } while (0)

    for (int kt = 0; kt <= ktmax; ++kt) {
        const bool more = (kt < ktmax);

        int4_ kpre[4], vpre[4];            // T14 issue-early
        if (more) {
            const int krow = (kt + 1) * 64;
#pragma unroll
            for (int pp = 0; pp < 4; ++pp) {
                kpre[pp] = *(const int4_*)&Kp[(size_t)(krow + kr + pp * 16) * 128 + kc];
                vpre[pp] = *(const int4_*)&Vp[(size_t)(krow + ln) * 128 + vd + pp * 8];
            }
        }

        float4_ sacc[2][4];
        if (kt <= dtlo) {
            // ---------- both frags active (shared kf/vf reads) ----------
            __builtin_amdgcn_s_setprio(1);
#pragma unroll
            for (int nf = 0; nf < 4; ++nf) {
                sacc[0][nf] = fzero; sacc[1][nf] = fzero;
#pragma unroll
                for (int ks = 0; ks < 4; ++ks) {
                    short8 kf = *(const short8*)&Ks[nf * 16 + r15][ks * 32 + quad * 8];
                    sacc[0][nf] = MFMA_BF16(qf[0][ks], kf, sacc[0][nf]);
                    sacc[1][nf] = MFMA_BF16(qf[1][ks], kf, sacc[1][nf]);
                }
            }
            __builtin_amdgcn_s_setprio(0);
            if (kt == dtlo) DIAGMASK(0);   // rf1 diagonal is kt==ktmax>dtlo
            SOFTMAX(0);
            SOFTMAX(1);
            __builtin_amdgcn_s_setprio(1);
#pragma unroll
            for (int k2 = 0; k2 < 2; ++k2) {
                short8 pf0 = *(const short8*)&Ps[wave][r15][k2 * 32 + quad * 8];
                short8 pf1 = *(const short8*)&Ps[wave][16 + r15][k2 * 32 + quad * 8];
#pragma unroll
                for (int of = 0; of < 8; ++of) {
                    short8 vf = *(const short8*)&Vt[of * 16 + r15][k2 * 32 + quad * 8];
                    acc_o[0][of] = MFMA_BF16(pf0, vf, acc_o[0][of]);
                    acc_o[1][of] = MFMA_BF16(pf1, vf, acc_o[1][of]);
                }
            }
            __builtin_amdgcn_s_setprio(0);
        } else {
            // ---------- hi frag only ----------
            __builtin_amdgcn_s_setprio(1);
#pragma unroll
            for (int nf = 0; nf < 4; ++nf) {
                sacc[1][nf] = fzero;
#pragma unroll
                for (int ks = 0; ks < 4; ++ks) {
                    short8 kf = *(const short8*)&Ks[nf * 16 + r15][ks * 32 + quad * 8];
                    sacc[1][nf] = MFMA_BF16(qf[1][ks], kf, sacc[1][nf]);
                }
            }
            __builtin_amdgcn_s_setprio(0);
            if (kt == ktmax) DIAGMASK(1);
            SOFTMAX(1);
            __builtin_amdgcn_s_setprio(1);
#pragma unroll
            for (int k2 = 0; k2 < 2; ++k2) {
                short8 pf1 = *(const short8*)&Ps[wave][16 + r15][k2 * 32 + quad * 8];
#pragma unroll
                for (int of = 0; of < 8; ++of) {
                    short8 vf = *(const short8*)&Vt[of * 16 + r15][k2 * 32 + quad * 8];
                    acc_o[1][of] = MFMA_BF16(pf1, vf, acc_o[1][of]);
                }
            }
            __builtin_amdgcn_s_setprio(0);
        }

        __syncthreads();                  // all waves done reading Ks/Vt
        if (more) {                       // T14 write-late
#pragma unroll
            for (int pp = 0; pp < 4; ++pp)
                *(int4_*)&Ks[kr + pp * 16][kc] = kpre[pp];
            union { int4_ v; bf16 h[8]; } u;
#pragma unroll
            for (int pp = 0; pp < 4; ++pp) {
                u.v = vpre[pp];
#pragma unroll
                for (int j = 0; j < 8; ++j) Vt[vd + pp * 8 + j][ln] = u.h[j];
            }
        }
        __syncthreads();
    }
#undef SOFTMAX
#undef DIAGMASK

    // epilogue: O[b][s][h][d], both frags
#pragma unroll
    for (int rf = 0; rf < 2; ++rf) {
        const int q0 = rf ? qhi : qlo;
#pragma unroll
        for (int r = 0; r < 4; ++r) {
            const float inv = 1.f / l_run[rf][r];
            const int  s  = q0 + quad * 4 + r;
            const size_t ob = (((size_t)b * S + s) * 16 + h) * 128;
#pragma unroll
            for (int of = 0; of < 8; ++of)
                Og[ob + of * 16 + r15] = f2bf(acc_o[rf][of][r] * inv);
        }
    }
}

// ---------------------------------------------------------------------------
extern "C" void kernel_launch(void* const* d_in, const int* in_sizes, int n_in,
                              void* d_out, int out_size, void* d_ws, size_t ws_size,
                              hipStream_t stream)
{
    const float* X  = (const float*)d_in[0];
    const float* Wq = (const float*)d_in[1];
    const float* Wk = (const float*)d_in[2];
    const float* Wv = (const float*)d_in[3];
    const float* Wo = (const float*)d_in[4];
    float* out = (float*)d_out;

    bf16* Xb  = (bf16*)d_ws;                 // 8388608
    bf16* Wqb = Xb  + 8388608;               // contiguous [6144][2048]: Wq,Wk,Wv
    bf16* Wkb = Wqb + 4194304;
    bf16* Wvb = Wkb + 4194304;
    bf16* Wob = Wvb + 4194304;
    bf16* q   = Wob + 4194304;               // contiguous [3][B][NH][S][HD]
    bf16* k   = q   + 8388608;
    bf16* v   = k   + 8388608;
    bf16* ao  = v   + 8388608;               // [B][S][NH][HD]
    float2* tab = (float2*)(ao + 8388608);   // rope cos/sin [2048][64], 1 MB

    dim3 blk(256);
    rope_tab<<<dim3(512), blk, 0, stream>>>(tab);
    cvt_all<<<dim3(12288), blk, 0, stream>>>(X, Wq, Wk, Wv, Wo,
                                             Xb, Wqb, Wkb, Wvb, Wob);
    // merged QKV: C[4096][6144] = Xb * [Wq;Wk;Wv]^T, 768 blocks = 3 rounds
    gemm_bn128<<<dim3(48, 16), dim3(512), 0, stream>>>(Xb, Wqb, q, nullptr, 0);
    rope_scale<<<dim3((2 * 16 * 2048 * 64) / 256), blk, 0, stream>>>(q, k, tab);
    // 64-row strip pairs (p, 31-p): 512 blocks, 33 units each, 2 blocks/CU
    flash_attn<<<dim3(16, 32), blk, 0, stream>>>(q, k, v, ao);
    // O-proj: C[4096][2048] = ao * Wo^T, 256 blocks = 1 full round
    gemm_bn128<<<dim3(16, 16), dim3(512), 0, stream>>>(ao, Wob, nullptr, out, 1);
}

// Round 9
// 470.162 us; speedup vs baseline: 1.0370x; 1.0370x over previous
//
#include <hip/hip_runtime.h>
#include <hip/hip_bf16.h>

using bf16 = __hip_bfloat16;
typedef short  short8  __attribute__((ext_vector_type(8)));
typedef float  float4_ __attribute__((ext_vector_type(4)));
typedef int    int4_   __attribute__((ext_vector_type(4)));

typedef __attribute__((address_space(1))) const void* gas_ptr;
typedef __attribute__((address_space(3))) void*       las_ptr;

#define MFMA_BF16(a, b, c) __builtin_amdgcn_mfma_f32_16x16x32_bf16((a), (b), (c), 0, 0, 0)

__device__ __forceinline__ float bf2f(bf16 v) { return __bfloat162float(v); }
__device__ __forceinline__ bf16  f2bf(float v) { return __float2bfloat16(v); }

#define BAR() do { asm volatile("" ::: "memory"); __builtin_amdgcn_s_barrier(); asm volatile("" ::: "memory"); } while (0)
#define WAITLGKM0() asm volatile("s_waitcnt lgkmcnt(0)" ::: "memory")

// ---------------------------------------------------------------------------
// DPP 16-lane reductions (verified r7): groups = lanes [quad*16..quad*16+15].
// ---------------------------------------------------------------------------
template<int CTRL>
__device__ __forceinline__ float dppmv(float x) {
    return __int_as_float(__builtin_amdgcn_update_dpp(
        0, __float_as_int(x), CTRL, 0xF, 0xF, true));
}
__device__ __forceinline__ float row16_max(float x) {
    x = fmaxf(x, dppmv<0xB1>(x));
    x = fmaxf(x, dppmv<0x4E>(x));
    x = fmaxf(x, dppmv<0x124>(x));
    x = fmaxf(x, dppmv<0x128>(x));
    return x;
}
__device__ __forceinline__ float row16_sum(float x) {
    x += dppmv<0xB1>(x);
    x += dppmv<0x4E>(x);
    x += dppmv<0x124>(x);
    x += dppmv<0x128>(x);
    return x;
}

// ---------------------------------------------------------------------------
// fp32 -> bf16 conversion of X + 4 weights into workspace (verified r2 form).
// ---------------------------------------------------------------------------
__global__ __launch_bounds__(256)
void cvt_all(const float* __restrict__ X,  const float* __restrict__ Wq,
             const float* __restrict__ Wk, const float* __restrict__ Wv,
             const float* __restrict__ Wo,
             bf16* __restrict__ Xb,  bf16* __restrict__ Wqb,
             bf16* __restrict__ Wkb, bf16* __restrict__ Wvb,
             bf16* __restrict__ Wob)
{
    const size_t i = ((size_t)blockIdx.x * 256 + threadIdx.x) * 8;
    const float* src; bf16* dst; size_t off;
    if (i < 8388608)       { src = X;  dst = Xb;  off = i; }
    else if (i < 12582912) { src = Wq; dst = Wqb; off = i - 8388608; }
    else if (i < 16777216) { src = Wk; dst = Wkb; off = i - 12582912; }
    else if (i < 20971520) { src = Wv; dst = Wvb; off = i - 16777216; }
    else                   { src = Wo; dst = Wob; off = i - 20971520; }
    const float4_ a = *(const float4_*)(src + off);
    const float4_ b = *(const float4_*)(src + off + 4);
    union { short8 s; bf16 h[8]; } u;
#pragma unroll
    for (int j = 0; j < 4; ++j) { u.h[j] = f2bf(a[j]); u.h[j + 4] = f2bf(b[j]); }
    *(short8*)(dst + off) = u.s;
}

// ---------------------------------------------------------------------------
// 256x128 4-phase-per-tile MFMA GEMM (m201 granularity: 4 phases/K-tile,
// one stage slot per phase, counted vmcnt):
//   quadrants (M0N0)->(M0N1)->(M1N1)->(M1N0); register reuse a0 across
//   ph1-2, b1 across ph2-3, b0 across ph1&ph4. Stage slots: B0(t+2)@ph2,
//   B1(t+2)@ph3, A(t+2)x4@ph4 - each one barrier after that region's last
//   ds_read. Steady-state vmcnt(6) at tile end drains tile t+1, leaves
//   t+2's 6 loads in flight; vmcnt(0) tail at t>=NT-2 (no newer loads back
//   the count). T2 swizzle + XCD swizzle + setprio verbatim from r4-r7.
// mode 0: scatter bf16 to Oq = q/k/v [3][B][NH][S][HD], N=6144 merged QKV.
// mode 1: row-major fp32 OF, N=2048.
// ---------------------------------------------------------------------------
__global__ __launch_bounds__(512, 2)
void gemm_bn128(const bf16* __restrict__ Ap, const bf16* __restrict__ Wp,
                bf16* __restrict__ Oq, float* __restrict__ OF, int mode)
{
    constexpr int NT = 32;                       // K=2048 / BK=64
    __shared__ bf16 As0[2 * 256 * 64];           // 64 KiB [buf][row][64]
    __shared__ bf16 Bs0[2 * 128 * 64];           // 32 KiB

    const int nwg  = gridDim.x * gridDim.y;
    const int bid0 = blockIdx.y * gridDim.x + blockIdx.x;
    const int cpx  = nwg >> 3;
    const int swzb = (bid0 & 7) * cpx + (bid0 >> 3);
    const int bn = (swzb % gridDim.x) * 128;
    const int bm = (swzb / gridDim.x) * 256;

    const int tid  = threadIdx.x;
    const int w    = tid >> 6;                   // 0..7
    const int ln   = tid & 63;
    const int r15  = ln & 15;
    const int quad = ln >> 4;
    const int wr   = w >> 1;                     // 0..3 (M)
    const int wc   = w & 1;                      // 0..1 (N)

    const int srow = ln >> 3;                                // 0..7
    const int scol = ((ln & 7) ^ srow) * 8;                  // elements
    const int w8   = w * 8;
    const int cx   = (r15 & 7) * 8;                          // read-side XOR

#define STAGE_A(pb, ts) do {                                                \
    _Pragma("unroll")                                                       \
    for (int c = 0; c < 4; ++c) {                                           \
        const int rl = c * 64 + w8;                                         \
        __builtin_amdgcn_global_load_lds(                                   \
            (gas_ptr)(Ap + (size_t)(bm + rl + srow) * 2048 + (ts) * 64 + scol), \
            (las_ptr)(As0 + (pb) * 16384 + rl * 64), 16, 0, 0);             \
    } } while (0)

#define STAGE_B0(pb, ts) do {                                               \
    const int rl = w8;                                                      \
    __builtin_amdgcn_global_load_lds(                                       \
        (gas_ptr)(Wp + (size_t)(bn + rl + srow) * 2048 + (ts) * 64 + scol), \
        (las_ptr)(Bs0 + (pb) * 8192 + rl * 64), 16, 0, 0);                  \
    } while (0)

#define STAGE_B1(pb, ts) do {                                               \
    const int rl = 64 + w8;                                                 \
    __builtin_amdgcn_global_load_lds(                                       \
        (gas_ptr)(Wp + (size_t)(bn + rl + srow) * 2048 + (ts) * 64 + scol), \
        (las_ptr)(Bs0 + (pb) * 8192 + rl * 64), 16, 0, 0);                  \
    } while (0)

// load M-half hm (2 row-frags x 2 kk) into dst
#define LDA_H(dst, hm) do {                                                 \
    _Pragma("unroll")                                                       \
    for (int j = 0; j < 2; ++j) {                                           \
        const int row = wr * 64 + ((hm) * 2 + j) * 16 + r15;                \
        dst[j][0] = *(const short8*)(As0 + p * 16384 + row * 64 + ((quad * 8) ^ cx));      \
        dst[j][1] = *(const short8*)(As0 + p * 16384 + row * 64 + ((32 + quad * 8) ^ cx)); \
    } } while (0)

// load N-half hn (2 col-frags x 2 kk) into dst
#define LDB_H(dst, hn) do {                                                 \
    _Pragma("unroll")                                                       \
    for (int j = 0; j < 2; ++j) {                                           \
        const int row = wc * 64 + ((hn) * 2 + j) * 16 + r15;                \
        dst[j][0] = *(const short8*)(Bs0 + p * 8192 + row * 64 + ((quad * 8) ^ cx));      \
        dst[j][1] = *(const short8*)(Bs0 + p * 8192 + row * 64 + ((32 + quad * 8) ^ cx)); \
    } } while (0)

// one quadrant: 2x2 frags x 2 kk = 8 MFMA
#define MMQ(am, bnv, mo, no) do {                                           \
    __builtin_amdgcn_s_setprio(1);                                          \
    _Pragma("unroll")                                                       \
    for (int i = 0; i < 2; ++i)                                             \
        _Pragma("unroll")                                                   \
        for (int j = 0; j < 2; ++j)                                         \
            _Pragma("unroll")                                               \
            for (int kk = 0; kk < 2; ++kk)                                  \
                acc[(mo) * 2 + i][(no) * 2 + j] =                           \
                    MFMA_BF16(am[i][kk], bnv[j][kk], acc[(mo) * 2 + i][(no) * 2 + j]); \
    __builtin_amdgcn_s_setprio(0); } while (0)

    float4_ acc[4][4];
    const float4_ fzero = {0.f, 0.f, 0.f, 0.f};
#pragma unroll
    for (int i = 0; i < 4; ++i)
#pragma unroll
        for (int j = 0; j < 4; ++j) acc[i][j] = fzero;

    short8 a0[2][2], a1[2][2], b0[2][2], b1[2][2];

    // prologue: tile0 fully (6) then tile1 fully (6); vmcnt(6) drains tile0.
    STAGE_A(0, 0); STAGE_B0(0, 0); STAGE_B1(0, 0);
    STAGE_A(1, 1); STAGE_B0(1, 1); STAGE_B1(1, 1);
    asm volatile("s_waitcnt vmcnt(6)" ::: "memory");
    BAR();

    for (int t = 0; t < NT; ++t) {
        const int p = t & 1;
        // ph1: (M0,N0). 8 ds_reads, no stage.
        LDA_H(a0, 0); LDB_H(b0, 0);
        BAR(); WAITLGKM0();
        MMQ(a0, b0, 0, 0);
        BAR();
        // ph2: (M0,N1). stage B0(t+2) -> buf p (B0 last read ph1).
        LDB_H(b1, 1);
        if (t + 2 < NT) STAGE_B0(p, t + 2);
        BAR(); WAITLGKM0();
        MMQ(a0, b1, 0, 1);
        BAR();
        // ph3: (M1,N1). stage B1(t+2) (B1 last read ph2).
        LDA_H(a1, 1);
        if (t + 2 < NT) STAGE_B1(p, t + 2);
        BAR(); WAITLGKM0();
        MMQ(a1, b1, 1, 1);
        BAR();
        // ph4: (M1,N0) from regs (a1 ph3, b0 ph1). stage A(t+2) (A last
        // read ph3). Tile-end counted drain: vmcnt(6) leaves t+2's 6 loads
        // in flight, drains t+1's; tail t>=NT-2 must drain fully.
        if (t + 2 < NT) STAGE_A(p, t + 2);
        BAR();
        MMQ(a1, b0, 1, 0);
        if (t >= NT - 2) { asm volatile("s_waitcnt vmcnt(0)" ::: "memory"); }
        else             { asm volatile("s_waitcnt vmcnt(6)" ::: "memory"); }
        BAR();
    }

#pragma unroll
    for (int mi = 0; mi < 4; ++mi) {
#pragma unroll
        for (int ni = 0; ni < 4; ++ni) {
#pragma unroll
            for (int r = 0; r < 4; ++r) {
                const int row = bm + wr * 64 + mi * 16 + quad * 4 + r;
                const int col = bn + wc * 64 + ni * 16 + r15;
                const float v = acc[mi][ni][r];
                if (mode == 0) {
                    const int z = col >> 11, c2 = col & 2047;
                    const int h = c2 >> 7, d = c2 & 127;
                    const int bb = row >> 11, s = row & 2047;
                    Oq[(size_t)z * 8388608 + (((size_t)bb * 16 + h) * 2048 + s) * 128 + d] = f2bf(v);
                } else {
                    OF[(size_t)row * 2048 + col] = v;
                }
            }
        }
    }
#undef STAGE_A
#undef STAGE_B0
#undef STAGE_B1
#undef LDA_H
#undef LDB_H
#undef MMQ
}

// ---------------------------------------------------------------------------
// RoPE cos/sin table (verified r8): tab[s][d], 1 MB, computed once.
// ---------------------------------------------------------------------------
__global__ __launch_bounds__(256)
void rope_tab(float2* __restrict__ tab)
{
    const int i = blockIdx.x * 256 + threadIdx.x;   // 0..131071
    const int d = i & 63;
    const int s = i >> 6;
    const float inv_freq = expf(-(float)d * (9.210340371976184f / 64.f));
    const float ang = (float)s * inv_freq;
    tab[i] = make_float2(cosf(ang), sinf(ang));
}

// ---------------------------------------------------------------------------
// RoPE on Q and K from table (verified r8); folds 1/sqrt(128) into Q.
// ---------------------------------------------------------------------------
__global__ __launch_bounds__(256)
void rope_scale(bf16* __restrict__ Q, bf16* __restrict__ Kb,
                const float2* __restrict__ tab)
{
    const int idx = blockIdx.x * 256 + threadIdx.x;
    const int d  = idx & 63;
    const int s  = (idx >> 6) & 2047;
    const int bh = idx >> 17;
    const size_t base = ((size_t)bh * 2048 + s) * 128;

    const float2 cs = tab[s * 64 + d];
    const float c = cs.x, sn = cs.y;
    const float sc = 0.08838834764831845f;

    const float q1 = bf2f(Q[base + d]), q2 = bf2f(Q[base + d + 64]);
    Q[base + d]      = f2bf((q1 * c - q2 * sn) * sc);
    Q[base + d + 64] = f2bf((q2 * c + q1 * sn) * sc);

    const float k1 = bf2f(Kb[base + d]), k2 = bf2f(Kb[base + d + 64]);
    Kb[base + d]      = f2bf(k1 * c - k2 * sn);
    Kb[base + d + 64] = f2bf(k2 * c + k1 * sn);
}

// ---------------------------------------------------------------------------
// Causal MFMA flash attention, v5 (REVERTED to r7-verified form: r8's v6
// 4-wave/2-frag variant regressed — VGPR 188 capped 2 waves/SIMD and doubled
// the per-wave serial softmax chain).
// Pair-balanced (pr, 15-pr), wave-per-strip (waves 0-3 lo / 4-7 hi, 32 rows
// per wave), shared kf/vf reads, DPP softmax, T13 defer-max, T14 async-STAGE.
// Q,K,V: [B][NH][S][HD] bf16 (Q pre-scaled); O: [B][S][NH][HD] bf16.
// ---------------------------------------------------------------------------
__global__ __launch_bounds__(512)
void flash_attn(const bf16* __restrict__ Qg, const bf16* __restrict__ Kg,
                const bf16* __restrict__ Vg, bf16* __restrict__ Og)
{
    constexpr int S = 2048;
    const int pr = blockIdx.x;            // 0..7: strip pair (pr, 15-pr)
    const int bh = blockIdx.y;
    const int b = bh >> 4, h = bh & 15;
    const size_t base = (size_t)bh * S * 128;
    const bf16* Qp = Qg + base;
    const bf16* Kp = Kg + base;
    const bf16* Vp = Vg + base;

    const int tid  = threadIdx.x;
    const int wave = tid >> 6;            // 0..7
    const int ln   = tid & 63;
    const int r15  = ln & 15;
    const int quad = ln >> 4;
    const int sid  = wave & 3;            // sub-strip index within strip
    const int hi   = wave >> 2;           // 0 = lo strip, 1 = hi strip

    __shared__ bf16 Ks[64][136];          // K tile, 17.0 KB
    __shared__ bf16 Vt[128][72];          // V tile transposed, 18.0 KB
    __shared__ bf16 Ps[8][32][72];        // per-wave P (2 row-frags), 36.9 KB

    const int strip = hi ? (15 - pr) : pr;
    const int qrow0 = strip * 128 + sid * 32;   // this wave's 32 rows
    const int dt    = qrow0 >> 6;               // diagonal K-tile
    const int ktmax = 2 * (15 - pr) + 1;        // staging range (hi strip)

    short8 qf[2][4];
#pragma unroll
    for (int rf = 0; rf < 2; ++rf)
#pragma unroll
        for (int ks = 0; ks < 4; ++ks)
            qf[rf][ks] = *(const short8*)&Qp[(size_t)(qrow0 + rf * 16 + r15) * 128
                                             + ks * 32 + quad * 8];

    float4_ acc_o[2][8];
    const float4_ fzero = {0.f, 0.f, 0.f, 0.f};
#pragma unroll
    for (int rf = 0; rf < 2; ++rf)
#pragma unroll
        for (int of = 0; of < 8; ++of) acc_o[rf][of] = fzero;
    float m_run[2][4], l_run[2][4];
#pragma unroll
    for (int rf = 0; rf < 2; ++rf)
#pragma unroll
        for (int r = 0; r < 4; ++r) { m_run[rf][r] = -__builtin_inff(); l_run[rf][r] = 0.f; }

    const int kr = tid >> 4;              // 0..31
    const int kc = (tid & 15) * 8;        // 0..120
    const int vd = wave * 16;

    {   // stage tile 0 synchronously
#pragma unroll
        for (int p = 0; p < 2; ++p)
            *(int4_*)&Ks[kr + p * 32][kc] =
                *(const int4_*)&Kp[(size_t)(kr + p * 32) * 128 + kc];
        union { int4_ v; bf16 h[8]; } u;
#pragma unroll
        for (int p = 0; p < 2; ++p) {
            u.v = *(const int4_*)&Vp[(size_t)ln * 128 + vd + p * 8];
#pragma unroll
            for (int j = 0; j < 8; ++j)
                Vt[vd + p * 8 + j][ln] = u.h[j];
        }
    }
    __syncthreads();

    for (int kt = 0; kt <= ktmax; ++kt) {
        const bool more = (kt < ktmax);

        int4_ kpre0, kpre1, vpre0, vpre1;  // T14 issue-early
        if (more) {
            const int krow = (kt + 1) * 64;
            kpre0 = *(const int4_*)&Kp[(size_t)(krow + kr) * 128 + kc];
            kpre1 = *(const int4_*)&Kp[(size_t)(krow + kr + 32) * 128 + kc];
            vpre0 = *(const int4_*)&Vp[(size_t)(krow + ln) * 128 + vd];
            vpre1 = *(const int4_*)&Vp[(size_t)(krow + ln) * 128 + vd + 8];
        }

        if (kt <= dt) {                   // wave-uniform causal skip
            // ---- QK^T: shared kf read feeds both row-frags ----
            float4_ sacc[2][4];
            __builtin_amdgcn_s_setprio(1);
#pragma unroll
            for (int nf = 0; nf < 4; ++nf) {
                sacc[0][nf] = fzero;
                sacc[1][nf] = fzero;
#pragma unroll
                for (int ks = 0; ks < 4; ++ks) {
                    short8 kf = *(const short8*)&Ks[nf * 16 + r15][ks * 32 + quad * 8];
                    sacc[0][nf] = MFMA_BF16(qf[0][ks], kf, sacc[0][nf]);
                    sacc[1][nf] = MFMA_BF16(qf[1][ks], kf, sacc[1][nf]);
                }
            }
            __builtin_amdgcn_s_setprio(0);

            if (kt == dt) {               // diagonal tile: element mask
#pragma unroll
                for (int rf = 0; rf < 2; ++rf) {
                    const int ro = (qrow0 & 63) + rf * 16 + quad * 4;
#pragma unroll
                    for (int nf = 0; nf < 4; ++nf) {
                        const int col = nf * 16 + r15;
#pragma unroll
                        for (int r = 0; r < 4; ++r)
                            if (col > ro + r) sacc[rf][nf][r] = -__builtin_inff();
                    }
                }
            }

            // ---- online softmax per row-frag (DPP reduce + defer-max) ----
#pragma unroll
            for (int rf = 0; rf < 2; ++rf) {
                float rm4[4];
                float g = 0.f;
#pragma unroll
                for (int r = 0; r < 4; ++r) {
                    float rm = fmaxf(fmaxf(sacc[rf][0][r], sacc[rf][1][r]),
                                     fmaxf(sacc[rf][2][r], sacc[rf][3][r]));
                    rm4[r] = row16_max(rm);
                    g = fmaxf(g, rm4[r] - m_run[rf][r]);
                }
                const bool resc = !__all(g <= 8.f);   // T13
                float mnew[4], alpha[4];
                if (resc) {
#pragma unroll
                    for (int r = 0; r < 4; ++r) {
                        mnew[r]  = fmaxf(m_run[rf][r], rm4[r]);
                        alpha[r] = __expf(m_run[rf][r] - mnew[r]);
                        m_run[rf][r] = mnew[r];
                    }
                } else {
#pragma unroll
                    for (int r = 0; r < 4; ++r) { mnew[r] = m_run[rf][r]; alpha[r] = 1.f; }
                }
                float rs[4] = {0.f, 0.f, 0.f, 0.f};
#pragma unroll
                for (int nf = 0; nf < 4; ++nf) {
#pragma unroll
                    for (int r = 0; r < 4; ++r) {
                        const float pp = __expf(sacc[rf][nf][r] - mnew[r]);
                        rs[r] += pp;
                        Ps[wave][rf * 16 + quad * 4 + r][nf * 16 + r15] = f2bf(pp);
                    }
                }
#pragma unroll
                for (int r = 0; r < 4; ++r) {
                    const float t = row16_sum(rs[r]);
                    l_run[rf][r] = resc ? (l_run[rf][r] * alpha[r] + t)
                                        : (l_run[rf][r] + t);
                }
                if (resc) {
#pragma unroll
                    for (int of = 0; of < 8; ++of)
#pragma unroll
                        for (int r = 0; r < 4; ++r)
                            acc_o[rf][of][r] *= alpha[r];
                }
            }

            // ---- PV: shared vf read feeds both row-frags ----
            __builtin_amdgcn_s_setprio(1);
#pragma unroll
            for (int k2 = 0; k2 < 2; ++k2) {
                short8 pf0 = *(const short8*)&Ps[wave][r15][k2 * 32 + quad * 8];
                short8 pf1 = *(const short8*)&Ps[wave][16 + r15][k2 * 32 + quad * 8];
#pragma unroll
                for (int of = 0; of < 8; ++of) {
                    short8 vf = *(const short8*)&Vt[of * 16 + r15][k2 * 32 + quad * 8];
                    acc_o[0][of] = MFMA_BF16(pf0, vf, acc_o[0][of]);
                    acc_o[1][of] = MFMA_BF16(pf1, vf, acc_o[1][of]);
                }
            }
            __builtin_amdgcn_s_setprio(0);
        }

        __syncthreads();                  // all waves done reading Ks/Vt
        if (more) {                       // T14 write-late
            *(int4_*)&Ks[kr][kc]      = kpre0;
            *(int4_*)&Ks[kr + 32][kc] = kpre1;
            union { int4_ v; bf16 h[8]; } u;
            u.v = vpre0;
#pragma unroll
            for (int j = 0; j < 8; ++j) Vt[vd + j][ln] = u.h[j];
            u.v = vpre1;
#pragma unroll
            for (int j = 0; j < 8; ++j) Vt[vd + 8 + j][ln] = u.h[j];
        }
        __syncthreads();
    }

    // epilogue: O[b][s][h][d], both row-frags
#pragma unroll
    for (int rf = 0; rf < 2; ++rf) {
#pragma unroll
        for (int r = 0; r < 4; ++r) {
            const float inv = 1.f / l_run[rf][r];
            const int  s  = qrow0 + rf * 16 + quad * 4 + r;
            const size_t ob = (((size_t)b * S + s) * 16 + h) * 128;
#pragma unroll
            for (int of = 0; of < 8; ++of)
                Og[ob + of * 16 + r15] = f2bf(acc_o[rf][of][r] * inv);
        }
    }
}

// ---------------------------------------------------------------------------
extern "C" void kernel_launch(void* const* d_in, const int* in_sizes, int n_in,
                              void* d_out, int out_size, void* d_ws, size_t ws_size,
                              hipStream_t stream)
{
    const float* X  = (const float*)d_in[0];
    const float* Wq = (const float*)d_in[1];
    const float* Wk = (const float*)d_in[2];
    const float* Wv = (const float*)d_in[3];
    const float* Wo = (const float*)d_in[4];
    float* out = (float*)d_out;

    bf16* Xb  = (bf16*)d_ws;                 // 8388608
    bf16* Wqb = Xb  + 8388608;               // contiguous [6144][2048]: Wq,Wk,Wv
    bf16* Wkb = Wqb + 4194304;
    bf16* Wvb = Wkb + 4194304;
    bf16* Wob = Wvb + 4194304;
    bf16* q   = Wob + 4194304;               // contiguous [3][B][NH][S][HD]
    bf16* k   = q   + 8388608;
    bf16* v   = k   + 8388608;
    bf16* ao  = v   + 8388608;               // [B][S][NH][HD]
    float2* tab = (float2*)(ao + 8388608);   // rope cos/sin [2048][64], 1 MB

    dim3 blk(256);
    rope_tab<<<dim3(512), blk, 0, stream>>>(tab);
    cvt_all<<<dim3(12288), blk, 0, stream>>>(X, Wq, Wk, Wv, Wo,
                                             Xb, Wqb, Wkb, Wvb, Wob);
    // merged QKV: C[4096][6144] = Xb * [Wq;Wk;Wv]^T, 768 blocks = 3 rounds
    gemm_bn128<<<dim3(48, 16), dim3(512), 0, stream>>>(Xb, Wqb, q, nullptr, 0);
    rope_scale<<<dim3((2 * 16 * 2048 * 64) / 256), blk, 0, stream>>>(q, k, tab);
    // pair-balanced causal flash, wave-per-strip: 256 blocks, 34 units each
    flash_attn<<<dim3(8, 32), dim3(512), 0, stream>>>(q, k, v, ao);
    // O-proj: C[4096][2048] = ao * Wo^T, 256 blocks = 1 full round
    gemm_bn128<<<dim3(16, 16), dim3(512), 0, stream>>>(ao, Wob, nullptr, out, 1);
}

// Round 10
// 418.286 us; speedup vs baseline: 1.1656x; 1.1240x over previous
//
#include <hip/hip_runtime.h>
#include <hip/hip_bf16.h>

using bf16 = __hip_bfloat16;
typedef short  short8  __attribute__((ext_vector_type(8)));
typedef float  float4_ __attribute__((ext_vector_type(4)));
typedef int    int4_   __attribute__((ext_vector_type(4)));

typedef __attribute__((address_space(1))) const void* gas_ptr;
typedef __attribute__((address_space(3))) void*       las_ptr;

#define MFMA_BF16(a, b, c) __builtin_amdgcn_mfma_f32_16x16x32_bf16((a), (b), (c), 0, 0, 0)

__device__ __forceinline__ float bf2f(bf16 v) { return __bfloat162float(v); }
__device__ __forceinline__ bf16  f2bf(float v) { return __float2bfloat16(v); }

#define BAR() do { asm volatile("" ::: "memory"); __builtin_amdgcn_s_barrier(); asm volatile("" ::: "memory"); } while (0)
#define WAITLGKM0() asm volatile("s_waitcnt lgkmcnt(0)" ::: "memory")

// ---------------------------------------------------------------------------
// DPP 16-lane reductions (verified r7): groups = lanes [quad*16..quad*16+15].
// ---------------------------------------------------------------------------
template<int CTRL>
__device__ __forceinline__ float dppmv(float x) {
    return __int_as_float(__builtin_amdgcn_update_dpp(
        0, __float_as_int(x), CTRL, 0xF, 0xF, true));
}
__device__ __forceinline__ float row16_max(float x) {
    x = fmaxf(x, dppmv<0xB1>(x));
    x = fmaxf(x, dppmv<0x4E>(x));
    x = fmaxf(x, dppmv<0x124>(x));
    x = fmaxf(x, dppmv<0x128>(x));
    return x;
}
__device__ __forceinline__ float row16_sum(float x) {
    x += dppmv<0xB1>(x);
    x += dppmv<0x4E>(x);
    x += dppmv<0x124>(x);
    x += dppmv<0x128>(x);
    return x;
}

// ---------------------------------------------------------------------------
// fp32 -> bf16 conversion of X + 4 weights (verified r2 form) + RoPE cos/sin
// table fused in (blocks >= 12288): saves one launch + gap.
// ---------------------------------------------------------------------------
__global__ __launch_bounds__(256)
void cvt_all(const float* __restrict__ X,  const float* __restrict__ Wq,
             const float* __restrict__ Wk, const float* __restrict__ Wv,
             const float* __restrict__ Wo,
             bf16* __restrict__ Xb,  bf16* __restrict__ Wqb,
             bf16* __restrict__ Wkb, bf16* __restrict__ Wvb,
             bf16* __restrict__ Wob, float2* __restrict__ tab)
{
    if (blockIdx.x >= 12288) {            // rope table: tab[s][d], 1 MB
        const int i = (blockIdx.x - 12288) * 256 + threadIdx.x;  // 0..131071
        const int d = i & 63;
        const int s = i >> 6;
        const float inv_freq = expf(-(float)d * (9.210340371976184f / 64.f));
        const float ang = (float)s * inv_freq;
        tab[i] = make_float2(cosf(ang), sinf(ang));
        return;
    }
    const size_t i = ((size_t)blockIdx.x * 256 + threadIdx.x) * 8;
    const float* src; bf16* dst; size_t off;
    if (i < 8388608)       { src = X;  dst = Xb;  off = i; }
    else if (i < 12582912) { src = Wq; dst = Wqb; off = i - 8388608; }
    else if (i < 16777216) { src = Wk; dst = Wkb; off = i - 12582912; }
    else if (i < 20971520) { src = Wv; dst = Wvb; off = i - 16777216; }
    else                   { src = Wo; dst = Wob; off = i - 20971520; }
    const float4_ a = *(const float4_*)(src + off);
    const float4_ b = *(const float4_*)(src + off + 4);
    union { short8 s; bf16 h[8]; } u;
#pragma unroll
    for (int j = 0; j < 4; ++j) { u.h[j] = f2bf(a[j]); u.h[j + 4] = f2bf(b[j]); }
    *(short8*)(dst + off) = u.s;
}

// ---------------------------------------------------------------------------
// 256x128 2-phase-per-tile MFMA GEMM — REVERTED to the r4-r7-verified K-loop
// (r9's 4-phase split regressed: 8 MFMA/barrier-pair vs 16 doubled barrier
// overhead; MfmaUtil 33.9->26.3). New in r10: wave N-fragment remap so each
// thread holds both RoPE-pair elements:
//   wave wc owns cols wc*32+{0,16} (ni=0,1, d<64) and wc*32+64+{0,16}
//   (ni=2,3, d+64) -> acc[mi][ni] / acc[mi][ni+2] are the (d, d+64) pair.
//   LDB(qn) row = wc*32 + qn*64 + j*16 + r15 (B0 region rows 0..63 for qn=0,
//   B1 rows 64..127 for qn=1 — stage regions/slots unchanged).
// Epilogue mode 0 applies RoPE in-register from tab (z,h block-uniform;
// z==0 also folds 1/sqrt(128)); mode 1 plain fp32 row-major.
// ---------------------------------------------------------------------------
__global__ __launch_bounds__(512, 2)
void gemm_bn128(const bf16* __restrict__ Ap, const bf16* __restrict__ Wp,
                bf16* __restrict__ Oq, float* __restrict__ OF,
                const float2* __restrict__ tab, int mode)
{
    constexpr int NT = 32;                       // K=2048 / BK=64
    __shared__ bf16 As0[2 * 256 * 64];           // 64 KiB [buf][row][64]
    __shared__ bf16 Bs0[2 * 128 * 64];           // 32 KiB

    const int nwg  = gridDim.x * gridDim.y;
    const int bid0 = blockIdx.y * gridDim.x + blockIdx.x;
    const int cpx  = nwg >> 3;
    const int swzb = (bid0 & 7) * cpx + (bid0 >> 3);
    const int bn = (swzb % gridDim.x) * 128;
    const int bm = (swzb / gridDim.x) * 256;

    const int tid  = threadIdx.x;
    const int w    = tid >> 6;                   // 0..7
    const int ln   = tid & 63;
    const int r15  = ln & 15;
    const int quad = ln >> 4;
    const int wr   = w >> 1;                     // 0..3 (M)
    const int wc   = w & 1;                      // 0..1 (N)

    const int srow = ln >> 3;                                // 0..7
    const int scol = ((ln & 7) ^ srow) * 8;                  // elements
    const int w8   = w * 8;
    const int cx   = (r15 & 7) * 8;                          // read-side XOR

#define STAGE_A(pb, ts) do {                                                \
    _Pragma("unroll")                                                       \
    for (int c = 0; c < 4; ++c) {                                           \
        const int rl = c * 64 + w8;                                         \
        __builtin_amdgcn_global_load_lds(                                   \
            (gas_ptr)(Ap + (size_t)(bm + rl + srow) * 2048 + (ts) * 64 + scol), \
            (las_ptr)(As0 + (pb) * 16384 + rl * 64), 16, 0, 0);             \
    } } while (0)

#define STAGE_B0(pb, ts) do {                                               \
    const int rl = w8;                                                      \
    __builtin_amdgcn_global_load_lds(                                       \
        (gas_ptr)(Wp + (size_t)(bn + rl + srow) * 2048 + (ts) * 64 + scol), \
        (las_ptr)(Bs0 + (pb) * 8192 + rl * 64), 16, 0, 0);                  \
    } while (0)

#define STAGE_B1(pb, ts) do {                                               \
    const int rl = 64 + w8;                                                 \
    __builtin_amdgcn_global_load_lds(                                       \
        (gas_ptr)(Wp + (size_t)(bn + rl + srow) * 2048 + (ts) * 64 + scol), \
        (las_ptr)(Bs0 + (pb) * 8192 + rl * 64), 16, 0, 0);                  \
    } while (0)

#define LDA() do {                                                          \
    _Pragma("unroll")                                                       \
    for (int mi = 0; mi < 4; ++mi) {                                        \
        const int row = wr * 64 + mi * 16 + r15;                            \
        a[mi][0] = *(const short8*)(As0 + p * 16384 + row * 64 + ((quad * 8) ^ cx));      \
        a[mi][1] = *(const short8*)(As0 + p * 16384 + row * 64 + ((32 + quad * 8) ^ cx)); \
    } } while (0)

// qn=0: rows wc*32+{0,16}+r15 (B0 region); qn=1: +64 (B1 region)
#define LDB(qn) do {                                                        \
    _Pragma("unroll")                                                       \
    for (int j = 0; j < 2; ++j) {                                           \
        const int row = wc * 32 + (qn) * 64 + j * 16 + r15;                 \
        b[j][0] = *(const short8*)(Bs0 + p * 8192 + row * 64 + ((quad * 8) ^ cx));      \
        b[j][1] = *(const short8*)(Bs0 + p * 8192 + row * 64 + ((32 + quad * 8) ^ cx)); \
    } } while (0)

#define MM(qn) do {                                                         \
    __builtin_amdgcn_s_setprio(1);                                          \
    _Pragma("unroll")                                                       \
    for (int mi = 0; mi < 4; ++mi)                                          \
        _Pragma("unroll")                                                   \
        for (int j = 0; j < 2; ++j)                                         \
            _Pragma("unroll")                                               \
            for (int kk = 0; kk < 2; ++kk)                                  \
                acc[mi][(qn) * 2 + j] =                                     \
                    MFMA_BF16(a[mi][kk], b[j][kk], acc[mi][(qn) * 2 + j]);  \
    __builtin_amdgcn_s_setprio(0); } while (0)

    float4_ acc[4][4];
    const float4_ fzero = {0.f, 0.f, 0.f, 0.f};
#pragma unroll
    for (int i = 0; i < 4; ++i)
#pragma unroll
        for (int j = 0; j < 4; ++j) acc[i][j] = fzero;

    short8 a[4][2], b[2][2];

    STAGE_A(0, 0); STAGE_B0(0, 0); STAGE_B1(0, 0);
    STAGE_A(1, 1); STAGE_B0(1, 1);
    asm volatile("s_waitcnt vmcnt(5)" ::: "memory");
    BAR();

    for (int t = 0; t < NT; ++t) {
        const int p = t & 1, pq = p ^ 1;
        LDA(); LDB(0);
        if (t + 1 < NT) STAGE_B1(pq, t + 1);
        asm volatile("s_waitcnt lgkmcnt(8)" ::: "memory");
        BAR(); WAITLGKM0();
        MM(0);
        BAR();
        LDB(1);
        if (t + 2 < NT) { STAGE_A(p, t + 2); STAGE_B0(p, t + 2); }
        BAR(); WAITLGKM0();
        MM(1);
        if (t >= NT - 2) { asm volatile("s_waitcnt vmcnt(0)" ::: "memory"); }
        else             { asm volatile("s_waitcnt vmcnt(5)" ::: "memory"); }
        BAR();
    }

    if (mode == 0) {
        // q/k/v scatter with fused RoPE. Block-uniform: z (0=q,1=k,2=v), h.
        const int z = bn >> 11;
        const int h = (bn >> 7) & 15;
        bf16* Ob = Oq + (size_t)z * 8388608;
        const float sc = 0.08838834764831845f;  // 1/sqrt(128), q only
#pragma unroll
        for (int mi = 0; mi < 4; ++mi) {
#pragma unroll
            for (int ni = 0; ni < 2; ++ni) {
                const int d = wc * 32 + ni * 16 + r15;     // 0..63
#pragma unroll
                for (int r = 0; r < 4; ++r) {
                    const int row = bm + wr * 64 + mi * 16 + quad * 4 + r;
                    const int bb = row >> 11, s = row & 2047;
                    float vlo = acc[mi][ni][r];
                    float vhi = acc[mi][ni + 2][r];
                    if (z < 2) {                           // RoPE on q,k
                        const float2 cs = tab[s * 64 + d];
                        const float lo = vlo * cs.x - vhi * cs.y;
                        const float hi = vhi * cs.x + vlo * cs.y;
                        vlo = lo; vhi = hi;
                        if (z == 0) { vlo *= sc; vhi *= sc; }
                    }
                    const size_t ob = (((size_t)bb * 16 + h) * 2048 + s) * 128 + d;
                    Ob[ob]      = f2bf(vlo);
                    Ob[ob + 64] = f2bf(vhi);
                }
            }
        }
    } else {
#pragma unroll
        for (int mi = 0; mi < 4; ++mi) {
#pragma unroll
            for (int ni = 0; ni < 4; ++ni) {
                const int col = bn + wc * 32 + (ni >> 1) * 64 + (ni & 1) * 16 + r15;
#pragma unroll
                for (int r = 0; r < 4; ++r) {
                    const int row = bm + wr * 64 + mi * 16 + quad * 4 + r;
                    OF[(size_t)row * 2048 + col] = acc[mi][ni][r];
                }
            }
        }
    }
#undef STAGE_A
#undef STAGE_B0
#undef STAGE_B1
#undef LDA
#undef LDB
#undef MM
}

// ---------------------------------------------------------------------------
// Causal MFMA flash attention, v5 (r7-verified, unchanged):
// pair-balanced (pr, 15-pr), wave-per-strip (waves 0-3 lo / 4-7 hi, 32 rows
// per wave), shared kf/vf reads, DPP softmax, T13 defer-max, T14 async-STAGE.
// Q,K,V: [B][NH][S][HD] bf16 (Q pre-scaled+roped in GEMM epilogue);
// O: [B][S][NH][HD] bf16.
// ---------------------------------------------------------------------------
__global__ __launch_bounds__(512)
void flash_attn(const bf16* __restrict__ Qg, const bf16* __restrict__ Kg,
                const bf16* __restrict__ Vg, bf16* __restrict__ Og)
{
    constexpr int S = 2048;
    const int pr = blockIdx.x;            // 0..7: strip pair (pr, 15-pr)
    const int bh = blockIdx.y;
    const int b = bh >> 4, h = bh & 15;
    const size_t base = (size_t)bh * S * 128;
    const bf16* Qp = Qg + base;
    const bf16* Kp = Kg + base;
    const bf16* Vp = Vg + base;

    const int tid  = threadIdx.x;
    const int wave = tid >> 6;            // 0..7
    const int ln   = tid & 63;
    const int r15  = ln & 15;
    const int quad = ln >> 4;
    const int sid  = wave & 3;            // sub-strip index within strip
    const int hi   = wave >> 2;           // 0 = lo strip, 1 = hi strip

    __shared__ bf16 Ks[64][136];          // K tile, 17.0 KB
    __shared__ bf16 Vt[128][72];          // V tile transposed, 18.0 KB
    __shared__ bf16 Ps[8][32][72];        // per-wave P (2 row-frags), 36.9 KB

    const int strip = hi ? (15 - pr) : pr;
    const int qrow0 = strip * 128 + sid * 32;   // this wave's 32 rows
    const int dt    = qrow0 >> 6;               // diagonal K-tile
    const int ktmax = 2 * (15 - pr) + 1;        // staging range (hi strip)

    short8 qf[2][4];
#pragma unroll
    for (int rf = 0; rf < 2; ++rf)
#pragma unroll
        for (int ks = 0; ks < 4; ++ks)
            qf[rf][ks] = *(const short8*)&Qp[(size_t)(qrow0 + rf * 16 + r15) * 128
                                             + ks * 32 + quad * 8];

    float4_ acc_o[2][8];
    const float4_ fzero = {0.f, 0.f, 0.f, 0.f};
#pragma unroll
    for (int rf = 0; rf < 2; ++rf)
#pragma unroll
        for (int of = 0; of < 8; ++of) acc_o[rf][of] = fzero;
    float m_run[2][4], l_run[2][4];
#pragma unroll
    for (int rf = 0; rf < 2; ++rf)
#pragma unroll
        for (int r = 0; r < 4; ++r) { m_run[rf][r] = -__builtin_inff(); l_run[rf][r] = 0.f; }

    const int kr = tid >> 4;              // 0..31
    const int kc = (tid & 15) * 8;        // 0..120
    const int vd = wave * 16;

    {   // stage tile 0 synchronously
#pragma unroll
        for (int p = 0; p < 2; ++p)
            *(int4_*)&Ks[kr + p * 32][kc] =
                *(const int4_*)&Kp[(size_t)(kr + p * 32) * 128 + kc];
        union { int4_ v; bf16 h[8]; } u;
#pragma unroll
        for (int p = 0; p < 2; ++p) {
            u.v = *(const int4_*)&Vp[(size_t)ln * 128 + vd + p * 8];
#pragma unroll
            for (int j = 0; j < 8; ++j)
                Vt[vd + p * 8 + j][ln] = u.h[j];
        }
    }
    __syncthreads();

    for (int kt = 0; kt <= ktmax; ++kt) {
        const bool more = (kt < ktmax);

        int4_ kpre0, kpre1, vpre0, vpre1;  // T14 issue-early
        if (more) {
            const int krow = (kt + 1) * 64;
            kpre0 = *(const int4_*)&Kp[(size_t)(krow + kr) * 128 + kc];
            kpre1 = *(const int4_*)&Kp[(size_t)(krow + kr + 32) * 128 + kc];
            vpre0 = *(const int4_*)&Vp[(size_t)(krow + ln) * 128 + vd];
            vpre1 = *(const int4_*)&Vp[(size_t)(krow + ln) * 128 + vd + 8];
        }

        if (kt <= dt) {                   // wave-uniform causal skip
            float4_ sacc[2][4];
            __builtin_amdgcn_s_setprio(1);
#pragma unroll
            for (int nf = 0; nf < 4; ++nf) {
                sacc[0][nf] = fzero;
                sacc[1][nf] = fzero;
#pragma unroll
                for (int ks = 0; ks < 4; ++ks) {
                    short8 kf = *(const short8*)&Ks[nf * 16 + r15][ks * 32 + quad * 8];
                    sacc[0][nf] = MFMA_BF16(qf[0][ks], kf, sacc[0][nf]);
                    sacc[1][nf] = MFMA_BF16(qf[1][ks], kf, sacc[1][nf]);
                }
            }
            __builtin_amdgcn_s_setprio(0);

            if (kt == dt) {               // diagonal tile: element mask
#pragma unroll
                for (int rf = 0; rf < 2; ++rf) {
                    const int ro = (qrow0 & 63) + rf * 16 + quad * 4;
#pragma unroll
                    for (int nf = 0; nf < 4; ++nf) {
                        const int col = nf * 16 + r15;
#pragma unroll
                        for (int r = 0; r < 4; ++r)
                            if (col > ro + r) sacc[rf][nf][r] = -__builtin_inff();
                    }
                }
            }

            // ---- online softmax per row-frag (DPP reduce + defer-max) ----
#pragma unroll
            for (int rf = 0; rf < 2; ++rf) {
                float rm4[4];
                float g = 0.f;
#pragma unroll
                for (int r = 0; r < 4; ++r) {
                    float rm = fmaxf(fmaxf(sacc[rf][0][r], sacc[rf][1][r]),
                                     fmaxf(sacc[rf][2][r], sacc[rf][3][r]));
                    rm4[r] = row16_max(rm);
                    g = fmaxf(g, rm4[r] - m_run[rf][r]);
                }
                const bool resc = !__all(g <= 8.f);   // T13
                float mnew[4], alpha[4];
                if (resc) {
#pragma unroll
                    for (int r = 0; r < 4; ++r) {
                        mnew[r]  = fmaxf(m_run[rf][r], rm4[r]);
                        alpha[r] = __expf(m_run[rf][r] - mnew[r]);
                        m_run[rf][r] = mnew[r];
                    }
                } else {
#pragma unroll
                    for (int r = 0; r < 4; ++r) { mnew[r] = m_run[rf][r]; alpha[r] = 1.f; }
                }
                float rs[4] = {0.f, 0.f, 0.f, 0.f};
#pragma unroll
                for (int nf = 0; nf < 4; ++nf) {
#pragma unroll
                    for (int r = 0; r < 4; ++r) {
                        const float pp = __expf(sacc[rf][nf][r] - mnew[r]);
                        rs[r] += pp;
                        Ps[wave][rf * 16 + quad * 4 + r][nf * 16 + r15] = f2bf(pp);
                    }
                }
#pragma unroll
                for (int r = 0; r < 4; ++r) {
                    const float t = row16_sum(rs[r]);
                    l_run[rf][r] = resc ? (l_run[rf][r] * alpha[r] + t)
                                        : (l_run[rf][r] + t);
                }
                if (resc) {
#pragma unroll
                    for (int of = 0; of < 8; ++of)
#pragma unroll
                        for (int r = 0; r < 4; ++r)
                            acc_o[rf][of][r] *= alpha[r];
                }
            }

            // ---- PV: shared vf read feeds both row-frags ----
            __builtin_amdgcn_s_setprio(1);
#pragma unroll
            for (int k2 = 0; k2 < 2; ++k2) {
                short8 pf0 = *(const short8*)&Ps[wave][r15][k2 * 32 + quad * 8];
                short8 pf1 = *(const short8*)&Ps[wave][16 + r15][k2 * 32 + quad * 8];
#pragma unroll
                for (int of = 0; of < 8; ++of) {
                    short8 vf = *(const short8*)&Vt[of * 16 + r15][k2 * 32 + quad * 8];
                    acc_o[0][of] = MFMA_BF16(pf0, vf, acc_o[0][of]);
                    acc_o[1][of] = MFMA_BF16(pf1, vf, acc_o[1][of]);
                }
            }
            __builtin_amdgcn_s_setprio(0);
        }

        __syncthreads();                  // all waves done reading Ks/Vt
        if (more) {                       // T14 write-late
            *(int4_*)&Ks[kr][kc]      = kpre0;
            *(int4_*)&Ks[kr + 32][kc] = kpre1;
            union { int4_ v; bf16 h[8]; } u;
            u.v = vpre0;
#pragma unroll
            for (int j = 0; j < 8; ++j) Vt[vd + j][ln] = u.h[j];
            u.v = vpre1;
#pragma unroll
            for (int j = 0; j < 8; ++j) Vt[vd + 8 + j][ln] = u.h[j];
        }
        __syncthreads();
    }

    // epilogue: O[b][s][h][d], both row-frags
#pragma unroll
    for (int rf = 0; rf < 2; ++rf) {
#pragma unroll
        for (int r = 0; r < 4; ++r) {
            const float inv = 1.f / l_run[rf][r];
            const int  s  = qrow0 + rf * 16 + quad * 4 + r;
            const size_t ob = (((size_t)b * S + s) * 16 + h) * 128;
#pragma unroll
            for (int of = 0; of < 8; ++of)
                Og[ob + of * 16 + r15] = f2bf(acc_o[rf][of][r] * inv);
        }
    }
}

// ---------------------------------------------------------------------------
extern "C" void kernel_launch(void* const* d_in, const int* in_sizes, int n_in,
                              void* d_out, int out_size, void* d_ws, size_t ws_size,
                              hipStream_t stream)
{
    const float* X  = (const float*)d_in[0];
    const float* Wq = (const float*)d_in[1];
    const float* Wk = (const float*)d_in[2];
    const float* Wv = (const float*)d_in[3];
    const float* Wo = (const float*)d_in[4];
    float* out = (float*)d_out;

    bf16* Xb  = (bf16*)d_ws;                 // 8388608
    bf16* Wqb = Xb  + 8388608;               // contiguous [6144][2048]: Wq,Wk,Wv
    bf16* Wkb = Wqb + 4194304;
    bf16* Wvb = Wkb + 4194304;
    bf16* Wob = Wvb + 4194304;
    bf16* q   = Wob + 4194304;               // contiguous [3][B][NH][S][HD]
    bf16* k   = q   + 8388608;
    bf16* v   = k   + 8388608;
    bf16* ao  = v   + 8388608;               // [B][S][NH][HD]
    float2* tab = (float2*)(ao + 8388608);   // rope cos/sin [2048][64], 1 MB

    dim3 blk(256);
    // cvt + rope-table fused (blocks 12288..12799 build the table)
    cvt_all<<<dim3(12800), blk, 0, stream>>>(X, Wq, Wk, Wv, Wo,
                                             Xb, Wqb, Wkb, Wvb, Wob, tab);
    // merged QKV with fused RoPE epilogue: 768 blocks = 3 rounds
    gemm_bn128<<<dim3(48, 16), dim3(512), 0, stream>>>(Xb, Wqb, q, nullptr, tab, 0);
    // pair-balanced causal flash, wave-per-strip: 256 blocks, 34 units each
    flash_attn<<<dim3(8, 32), dim3(512), 0, stream>>>(q, k, v, ao);
    // O-proj: C[4096][2048] = ao * Wo^T, 256 blocks = 1 full round
    gemm_bn128<<<dim3(16, 16), dim3(512), 0, stream>>>(ao, Wob, nullptr, out, tab, 1);
}